// Round 2
// 1635.785 us; speedup vs baseline: 1.2710x; 1.2710x over previous
//
#include <hip/hip_runtime.h>
#include <cstdint>

#define Tt 512
#define Bb 512
#define Ii 128
#define Hh 128
#define G4 512   // 4*H
#define S1 65    // stack slots
#define NSTEP 511
#define GROWS 128  // x rows staged per gx block

typedef float v2f __attribute__((ext_vector_type(2)));

__device__ __forceinline__ v2f fma2(v2f a, v2f b, v2f c) {
    return __builtin_elementwise_fma(a, b, c);
}
__device__ __forceinline__ float sigm(float x) {
    float e = __builtin_amdgcn_exp2f(x * -1.442695041f);
    return __builtin_amdgcn_rcpf(1.0f + e);
}
__device__ __forceinline__ float tanhx(float x) {
    float e = __builtin_amdgcn_exp2f(x * 2.885390082f);   // exp(2x)
    return 1.0f - 2.0f * __builtin_amdgcn_rcpf(e + 1.0f);
}

// add value from lane (l + N) within the 16-lane DPP row (row_shl:N);
// accumulates toward the LOW lane of each group. old=0 covers OOR lanes.
template <int CTRL>
__device__ __forceinline__ float dpp_add(float v) {
    int t = __builtin_amdgcn_update_dpp(0, __float_as_int(v), CTRL, 0xF, 0xF, true);
    return v + __int_as_float(t);
}
// sum over the 8 lanes of a ko-group; valid at lanes with (lane&7)==0
__device__ __forceinline__ float red8(float v) {
    v = dpp_add<0x104>(v);  // row_shl:4  (lane i += lane i+4)
    v = dpp_add<0x102>(v);  // row_shl:2
    v = dpp_add<0x101>(v);  // row_shl:1
    return v;
}

// Thread layout (both kernels): h = tid>>3 (0..127), ko = tid&7.
// Thread owns gate rows {h, h+128, h+256, h+384} restricted to k-quads
// {ko, 8+ko, 16+ko, 24+ko} (float4 units) -> 64 weight floats in VGPRs.
// LDS row reads: 4 x ds_read_b128, 8 distinct bank-quads per wave (conflict-free).

// ---------------- Input GEMM: gx[b][s][h] = float4 of 4 gates (+bias) --------
__global__ __launch_bounds__(1024, 4) void gx_gemm(
    const float* __restrict__ x,      // (rows, 128), chunk base
    const float* __restrict__ W_ih,   // (512, 128)
    const float* __restrict__ b_ih,
    const float* __restrict__ b_hh,
    float* __restrict__ gx,           // float4[(b*chcap + s)*128 + h]
    int chcap)
{
    const int tid = threadIdx.x;
    const int h = tid >> 3;
    const int ko = tid & 7;

    v2f wv[4][8];
#pragma unroll
    for (int q = 0; q < 4; ++q) {
        const float4* wr = (const float4*)(W_ih + (size_t)(h + 128 * q) * Ii);
#pragma unroll
        for (int i = 0; i < 4; ++i) {
            float4 w4 = wr[i * 8 + ko];
            wv[q][2 * i]     = (v2f){w4.x, w4.y};
            wv[q][2 * i + 1] = (v2f){w4.z, w4.w};
        }
    }
#pragma unroll
    for (int q = 0; q < 4; ++q)
#pragma unroll
        for (int i = 0; i < 8; ++i) asm volatile("" : "+v"(wv[q][i]));

    float4 bias;
    bias.x = b_ih[h]       + b_hh[h];
    bias.y = b_ih[h + 128] + b_hh[h + 128];
    bias.z = b_ih[h + 256] + b_hh[h + 256];
    bias.w = b_ih[h + 384] + b_hh[h + 384];

    __shared__ float xs[GROWS * Ii];  // 64 KB
    const int m0 = blockIdx.x * GROWS;
    {
        const float4* src = (const float4*)(x + (size_t)m0 * Ii);
        float4* dst = (float4*)xs;
#pragma unroll
        for (int j = 0; j < 4; ++j) dst[tid + j * 1024] = src[tid + j * 1024];
    }
    __syncthreads();

    float4* gxq = (float4*)gx;
    for (int mi = 0; mi < GROWS; ++mi) {
        const float4* xr = (const float4*)(xs + mi * Ii);
        v2f a0 = {0.f, 0.f}, a1 = a0, a2 = a0, a3 = a0;
#pragma unroll
        for (int i = 0; i < 4; ++i) {
            float4 xx = xr[i * 8 + ko];
            v2f lo = {xx.x, xx.y}, hi = {xx.z, xx.w};
            a0 = fma2(wv[0][2 * i], lo, a0); a0 = fma2(wv[0][2 * i + 1], hi, a0);
            a1 = fma2(wv[1][2 * i], lo, a1); a1 = fma2(wv[1][2 * i + 1], hi, a1);
            a2 = fma2(wv[2][2 * i], lo, a2); a2 = fma2(wv[2][2 * i + 1], hi, a2);
            a3 = fma2(wv[3][2 * i], lo, a3); a3 = fma2(wv[3][2 * i + 1], hi, a3);
        }
        float s0 = red8(a0.x + a0.y);
        float s1 = red8(a1.x + a1.y);
        float s2 = red8(a2.x + a2.y);
        float s3 = red8(a3.x + a3.y);
        if (ko == 0) {
            const int m = m0 + mi;          // chunk-local row: m = s*512 + b
            const int s = m >> 9;
            const int bb = m & 511;
            gxq[((size_t)bb * chcap + s) * Hh + h] =
                make_float4(s0 + bias.x, s1 + bias.y, s2 + bias.z, s3 + bias.w);
        }
    }
}

// ---------------- Recurrence: one block (1024 thr) per batch element --------
__global__ __launch_bounds__(1024, 4) void rec_step(
    const float* __restrict__ gxc,    // float4[(b*chcap + s)*128 + h]
    const int* __restrict__ ops,      // (T, B)
    const float* __restrict__ W_hh,   // (512, 128)
    const float* __restrict__ init_h,
    const float* __restrict__ init_c,
    float* __restrict__ out,          // (NSTEP, B, H)
    float* __restrict__ h_save,
    float* __restrict__ c_save,
    int* __restrict__ pt_save,
    int t0, int steps, int chcap, int first, int last)
{
    const int b = blockIdx.x;
    const int tid = threadIdx.x;
    const int h = tid >> 3;
    const int ko = tid & 7;

    __shared__ float h_st[S1 * Hh];   // 33.3 KB
    __shared__ float c_st[S1 * Hh];   // 33.3 KB
    __shared__ float4 g4[Hh];         // 2 KB reduced gates
    __shared__ int opsb[NSTEP + 1];   // 2 KB

    v2f wv[4][8];
#pragma unroll
    for (int q = 0; q < 4; ++q) {
        const float4* wr = (const float4*)(W_hh + (size_t)(h + 128 * q) * Hh);
#pragma unroll
        for (int i = 0; i < 4; ++i) {
            float4 w4 = wr[i * 8 + ko];
            wv[q][2 * i]     = (v2f){w4.x, w4.y};
            wv[q][2 * i + 1] = (v2f){w4.z, w4.w};
        }
    }
#pragma unroll
    for (int q = 0; q < 4; ++q)
#pragma unroll
        for (int i = 0; i < 8; ++i) asm volatile("" : "+v"(wv[q][i]));

    if (first) {
        for (int i = tid; i < S1 * Hh; i += 1024) {
            h_st[i] = (i < Hh) ? init_h[i] : 0.f;
            c_st[i] = (i < Hh) ? init_c[i] : 0.f;
        }
    } else {
        const float* hs = h_save + (size_t)b * (S1 * Hh);
        const float* cs = c_save + (size_t)b * (S1 * Hh);
        for (int i = tid; i < S1 * Hh; i += 1024) { h_st[i] = hs[i]; c_st[i] = cs[i]; }
    }
    for (int i = tid; i <= steps; i += 1024) opsb[i] = ops[(size_t)(t0 + i) * Bb + b];
    int pt = first ? 0 : pt_save[b];

    const float4* gxq = (const float4*)gxc + (size_t)b * chcap * Hh;
    float4 gxv = make_float4(0.f, 0.f, 0.f, 0.f);
    if (tid < Hh) gxv = gxq[tid];     // step 0, coalesced
    __syncthreads();

    for (int s = 0; s < steps; ++s) {
        // prefetch next step's gx (cell waves only; ~full step to cover latency)
        float4 gxn;
        if (tid < Hh) {
            const int sn = (s + 1 < steps) ? (s + 1) : s;
            gxn = gxq[(size_t)sn * Hh + tid];
        }

        pt += opsb[s];
        const float4* hq = (const float4*)(h_st + pt * Hh);
        v2f a0 = {0.f, 0.f}, a1 = a0, a2 = a0, a3 = a0;
#pragma unroll
        for (int i = 0; i < 4; ++i) {
            float4 hx = hq[i * 8 + ko];
            v2f lo = {hx.x, hx.y}, hi = {hx.z, hx.w};
            a0 = fma2(wv[0][2 * i], lo, a0); a0 = fma2(wv[0][2 * i + 1], hi, a0);
            a1 = fma2(wv[1][2 * i], lo, a1); a1 = fma2(wv[1][2 * i + 1], hi, a1);
            a2 = fma2(wv[2][2 * i], lo, a2); a2 = fma2(wv[2][2 * i + 1], hi, a2);
            a3 = fma2(wv[3][2 * i], lo, a3); a3 = fma2(wv[3][2 * i + 1], hi, a3);
        }
        float s0 = red8(a0.x + a0.y);
        float s1 = red8(a1.x + a1.y);
        float s2 = red8(a2.x + a2.y);
        float s3 = red8(a3.x + a3.y);
        if (ko == 0) g4[h] = make_float4(s0, s1, s2, s3);
        __syncthreads();

        if (tid < Hh) {               // waves 0,1: full LSTM cell, one h each
            const float4 gg = g4[tid];
            const float gi = gg.x + gxv.x;
            const float gf = gg.y + gxv.y;
            const float gG = gg.z + gxv.z;
            const float go = gg.w + gxv.w;
            const float cc = c_st[pt * Hh + tid];
            const float ch = h_st[pt * Hh + tid];
            const int pv = pt ? (pt - 1) : (S1 - 1);
            const float ph = h_st[pv * Hh + tid];
            const float nc = sigm(gf) * cc + sigm(gi) * tanhx(gG);
            const float nh = sigm(go) * tanhx(nc);
            c_st[(pt + 1) * Hh + tid] = nc;
            h_st[(pt + 1) * Hh + tid] = nh;
            const float opf = (float)opsb[s + 1];
            const float af = fabsf(opf);
            const float ret = (nh * (1.f + opf) + ph * (1.f - opf)) * af + ch * (1.f - af);
            out[((size_t)(t0 + s) * Bb + b) * Hh + tid] = ret;
            gxv = gxn;
        }
        __syncthreads();
    }

    if (!last) {
        float* hs = h_save + (size_t)b * (S1 * Hh);
        float* cs = c_save + (size_t)b * (S1 * Hh);
        for (int i = tid; i < S1 * Hh; i += 1024) { hs[i] = h_st[i]; cs[i] = c_st[i]; }
        if (tid == 0) pt_save[b] = pt;
    }
}

extern "C" void kernel_launch(void* const* d_in, const int* in_sizes, int n_in,
                              void* d_out, int out_size, void* d_ws, size_t ws_size,
                              hipStream_t stream) {
    const float* inputs = (const float*)d_in[0];
    const int*   ops    = (const int*)d_in[1];
    const float* W_ih   = (const float*)d_in[2];
    const float* W_hh   = (const float*)d_in[3];
    const float* b_ih   = (const float*)d_in[4];
    const float* b_hh   = (const float*)d_in[5];
    const float* init_h = (const float*)d_in[6];
    const float* init_c = (const float*)d_in[7];
    float* out = (float*)d_out;

    // Adaptive chunking: if workspace fits the full (511,512,512) gx buffer
    // (~536 MB), do ONE chunk -> no h/c save/restore traffic at all.
    float* ws = (float*)d_ws;
    const size_t gx_full = (size_t)NSTEP * Bb * G4;              // floats
    const size_t save_f  = 2 * (size_t)Bb * S1 * Hh + 512;       // floats
    const size_t ws_f = ws_size / sizeof(float);

    int chcap;
    float *gxbuf, *h_sv, *c_sv;
    int* pt_sv;
    if (ws_f >= gx_full) {
        chcap = NSTEP;
        gxbuf = ws; h_sv = ws; c_sv = ws; pt_sv = (int*)ws;      // save bufs unused
    } else {
        h_sv  = ws;
        c_sv  = h_sv + (size_t)Bb * S1 * Hh;
        pt_sv = (int*)(c_sv + (size_t)Bb * S1 * Hh);
        gxbuf = (float*)(pt_sv + 512);                           // 16B-aligned
        const size_t avail = ws_f > save_f ? ws_f - save_f : 0;
        size_t cc = avail / ((size_t)Bb * G4);
        if (cc < 1) cc = 1;
        chcap = (cc > NSTEP) ? NSTEP : (int)cc;
    }

    int t0 = 0;
    while (t0 < NSTEP) {
        const int steps = (NSTEP - t0 < chcap) ? (NSTEP - t0) : chcap;
        gx_gemm<<<steps * Bb / GROWS, 1024, 0, stream>>>(
            inputs + (size_t)t0 * Bb * Ii, W_ih, b_ih, b_hh, gxbuf, chcap);
        rec_step<<<Bb, 1024, 0, stream>>>(
            gxbuf, ops, W_hh, init_h, init_c, out,
            h_sv, c_sv, pt_sv, t0, steps, chcap,
            (t0 == 0) ? 1 : 0, (t0 + steps >= NSTEP) ? 1 : 0);
        t0 += steps;
    }
}

// Round 3
// 1397.125 us; speedup vs baseline: 1.4881x; 1.1708x over previous
//
#include <hip/hip_runtime.h>
#include <cstdint>

#define Tt 512
#define Bb 512
#define Ii 128
#define Hh 128
#define G4 512   // 4*H
#define S1 65    // stack slots
#define NSTEP 511
#define GROWS 128  // x rows staged per gx block

typedef float v2f __attribute__((ext_vector_type(2)));

__device__ __forceinline__ v2f fma2(v2f a, v2f b, v2f c) {
    return __builtin_elementwise_fma(a, b, c);
}
__device__ __forceinline__ float sigm(float x) {
    float e = __builtin_amdgcn_exp2f(x * -1.442695041f);
    return __builtin_amdgcn_rcpf(1.0f + e);
}
__device__ __forceinline__ float tanhx(float x) {
    float e = __builtin_amdgcn_exp2f(x * 2.885390082f);   // exp(2x)
    return 1.0f - 2.0f * __builtin_amdgcn_rcpf(e + 1.0f);
}

// add value from lane (l + N) within the 16-lane DPP row (row_shl:N);
// accumulates toward the LOW lane of each group. old=0 covers OOR lanes.
template <int CTRL>
__device__ __forceinline__ float dpp_add(float v) {
    int t = __builtin_amdgcn_update_dpp(0, __float_as_int(v), CTRL, 0xF, 0xF, true);
    return v + __int_as_float(t);
}
// sum over the 8 lanes of a ko-group; valid at lanes with (lane&7)==0
__device__ __forceinline__ float red8(float v) {
    v = dpp_add<0x104>(v);  // row_shl:4  (lane i += lane i+4)
    v = dpp_add<0x102>(v);  // row_shl:2
    v = dpp_add<0x101>(v);  // row_shl:1
    return v;
}

// Thread layout (both kernels): h = tid>>3 (0..127), ko = tid&7.
// Thread owns gate rows {h, h+128, h+256, h+384} restricted to k-quads
// {ko, 8+ko, 16+ko, 24+ko} (float4 units) -> 64 weight floats in VGPRs.
// LDS row reads: 4 x ds_read_b128, 8 distinct bank-quads per wave (conflict-free).

// ---------------- Input GEMM: gx[b][s][h] = float4 of 4 gates (+bias) --------
__global__ __launch_bounds__(1024, 4) void gx_gemm(
    const float* __restrict__ x,      // (rows, 128), chunk base
    const float* __restrict__ W_ih,   // (512, 128)
    const float* __restrict__ b_ih,
    const float* __restrict__ b_hh,
    float* __restrict__ gx,           // float4[(b*chcap + s)*128 + h]
    int chcap)
{
    const int tid = threadIdx.x;
    const int h = tid >> 3;
    const int ko = tid & 7;

    v2f wv[4][8];
#pragma unroll
    for (int q = 0; q < 4; ++q) {
        const float4* wr = (const float4*)(W_ih + (size_t)(h + 128 * q) * Ii);
#pragma unroll
        for (int i = 0; i < 4; ++i) {
            float4 w4 = wr[i * 8 + ko];
            wv[q][2 * i]     = (v2f){w4.x, w4.y};
            wv[q][2 * i + 1] = (v2f){w4.z, w4.w};
        }
    }
#pragma unroll
    for (int q = 0; q < 4; ++q)
#pragma unroll
        for (int i = 0; i < 8; ++i) asm volatile("" : "+v"(wv[q][i]));

    float4 bias;
    bias.x = b_ih[h]       + b_hh[h];
    bias.y = b_ih[h + 128] + b_hh[h + 128];
    bias.z = b_ih[h + 256] + b_hh[h + 256];
    bias.w = b_ih[h + 384] + b_hh[h + 384];

    __shared__ float xs[GROWS * Ii];  // 64 KB
    const int m0 = blockIdx.x * GROWS;
    {
        const float4* src = (const float4*)(x + (size_t)m0 * Ii);
        float4* dst = (float4*)xs;
#pragma unroll
        for (int j = 0; j < 4; ++j) dst[tid + j * 1024] = src[tid + j * 1024];
    }
    __syncthreads();

    float4* gxq = (float4*)gx;
    for (int mi = 0; mi < GROWS; ++mi) {
        const float4* xr = (const float4*)(xs + mi * Ii);
        v2f a0 = {0.f, 0.f}, a1 = a0, a2 = a0, a3 = a0;
#pragma unroll
        for (int i = 0; i < 4; ++i) {
            float4 xx = xr[i * 8 + ko];
            v2f lo = {xx.x, xx.y}, hi = {xx.z, xx.w};
            a0 = fma2(wv[0][2 * i], lo, a0); a0 = fma2(wv[0][2 * i + 1], hi, a0);
            a1 = fma2(wv[1][2 * i], lo, a1); a1 = fma2(wv[1][2 * i + 1], hi, a1);
            a2 = fma2(wv[2][2 * i], lo, a2); a2 = fma2(wv[2][2 * i + 1], hi, a2);
            a3 = fma2(wv[3][2 * i], lo, a3); a3 = fma2(wv[3][2 * i + 1], hi, a3);
        }
        float s0 = red8(a0.x + a0.y);
        float s1 = red8(a1.x + a1.y);
        float s2 = red8(a2.x + a2.y);
        float s3 = red8(a3.x + a3.y);
        if (ko == 0) {
            const int m = m0 + mi;          // chunk-local row: m = s*512 + b
            const int s = m >> 9;
            const int bb = m & 511;
            gxq[((size_t)bb * chcap + s) * Hh + h] =
                make_float4(s0 + bias.x, s1 + bias.y, s2 + bias.z, s3 + bias.w);
        }
    }
}

// ---------------- Recurrence: one block (1024 thr) per TWO batch elements ----
// 256 blocks -> exactly 1 per CU, all co-resident. The per-step fixed cost
// (2 barriers + cell-phase latency chain) is amortized over 2 batches, and
// the two matvecs give each SIMD twice the independent work to hide latency.
__global__ __launch_bounds__(1024, 4) void rec_step(
    const float* __restrict__ gxc,    // float4[(b*chcap + s)*128 + h]
    const int* __restrict__ ops,      // (T, B)
    const float* __restrict__ W_hh,   // (512, 128)
    const float* __restrict__ init_h,
    const float* __restrict__ init_c,
    float* __restrict__ out,          // (NSTEP, B, H)
    float* __restrict__ h_save,
    float* __restrict__ c_save,
    int* __restrict__ pt_save,
    int t0, int steps, int chcap, int first, int last)
{
    const int b0 = 2 * blockIdx.x;
    const int tid = threadIdx.x;
    const int h = tid >> 3;
    const int ko = tid & 7;

    __shared__ float h_st0[S1 * Hh];  // 33.25 KB each
    __shared__ float c_st0[S1 * Hh];
    __shared__ float h_st1[S1 * Hh];
    __shared__ float c_st1[S1 * Hh];
    __shared__ float4 g4[2][Hh];      // 4 KB reduced gates
    __shared__ int opsb[2][NSTEP + 1];// 4 KB

    v2f wv[4][8];
#pragma unroll
    for (int q = 0; q < 4; ++q) {
        const float4* wr = (const float4*)(W_hh + (size_t)(h + 128 * q) * Hh);
#pragma unroll
        for (int i = 0; i < 4; ++i) {
            float4 w4 = wr[i * 8 + ko];
            wv[q][2 * i]     = (v2f){w4.x, w4.y};
            wv[q][2 * i + 1] = (v2f){w4.z, w4.w};
        }
    }
#pragma unroll
    for (int q = 0; q < 4; ++q)
#pragma unroll
        for (int i = 0; i < 8; ++i) asm volatile("" : "+v"(wv[q][i]));

    if (first) {
        for (int i = tid; i < S1 * Hh; i += 1024) {
            const float hv = (i < Hh) ? init_h[i] : 0.f;
            const float cv = (i < Hh) ? init_c[i] : 0.f;
            h_st0[i] = hv; h_st1[i] = hv;
            c_st0[i] = cv; c_st1[i] = cv;
        }
    } else {
        const float* hs0 = h_save + (size_t)b0 * (S1 * Hh);
        const float* cs0 = c_save + (size_t)b0 * (S1 * Hh);
        const float* hs1 = hs0 + (S1 * Hh);
        const float* cs1 = cs0 + (S1 * Hh);
        for (int i = tid; i < S1 * Hh; i += 1024) {
            h_st0[i] = hs0[i]; c_st0[i] = cs0[i];
            h_st1[i] = hs1[i]; c_st1[i] = cs1[i];
        }
    }
    for (int i = tid; i <= steps; i += 1024) {
        const int2 o2 = *(const int2*)(ops + (size_t)(t0 + i) * Bb + b0);
        opsb[0][i] = o2.x;
        opsb[1][i] = o2.y;
    }
    int pt0 = 0, pt1 = 0;
    if (!first) { pt0 = pt_save[b0]; pt1 = pt_save[b0 + 1]; }

    // gx bases (per batch), cell-phase private prefetch registers
    const int bl = tid >> 7;          // 0 or 1 for cell threads (tid<256)
    const int hh = tid & 127;
    const float4* gq = (const float4*)gxc + ((size_t)(b0 + bl)) * chcap * Hh;
    float4 gxv = make_float4(0.f, 0.f, 0.f, 0.f);
    if (tid < 256) gxv = gq[hh];      // step 0
    __syncthreads();

    for (int s = 0; s < steps; ++s) {
        // prefetch next step's gx (cell threads only; covered by matvec phase)
        float4 gxn;
        if (tid < 256) {
            const int sn = (s + 1 < steps) ? (s + 1) : s;
            gxn = gq[(size_t)sn * Hh + hh];
        }

        pt0 += opsb[0][s];
        pt1 += opsb[1][s];

        // ---- matvec batch 0 ----
        {
            const float4* hq = (const float4*)(h_st0 + pt0 * Hh);
            v2f a0 = {0.f, 0.f}, a1 = a0, a2 = a0, a3 = a0;
#pragma unroll
            for (int i = 0; i < 4; ++i) {
                float4 hx = hq[i * 8 + ko];
                v2f lo = {hx.x, hx.y}, hi = {hx.z, hx.w};
                a0 = fma2(wv[0][2 * i], lo, a0); a0 = fma2(wv[0][2 * i + 1], hi, a0);
                a1 = fma2(wv[1][2 * i], lo, a1); a1 = fma2(wv[1][2 * i + 1], hi, a1);
                a2 = fma2(wv[2][2 * i], lo, a2); a2 = fma2(wv[2][2 * i + 1], hi, a2);
                a3 = fma2(wv[3][2 * i], lo, a3); a3 = fma2(wv[3][2 * i + 1], hi, a3);
            }
            float s0 = red8(a0.x + a0.y);
            float s1 = red8(a1.x + a1.y);
            float s2 = red8(a2.x + a2.y);
            float s3 = red8(a3.x + a3.y);
            if (ko == 0) g4[0][h] = make_float4(s0, s1, s2, s3);
        }
        // ---- matvec batch 1 ----
        {
            const float4* hq = (const float4*)(h_st1 + pt1 * Hh);
            v2f a0 = {0.f, 0.f}, a1 = a0, a2 = a0, a3 = a0;
#pragma unroll
            for (int i = 0; i < 4; ++i) {
                float4 hx = hq[i * 8 + ko];
                v2f lo = {hx.x, hx.y}, hi = {hx.z, hx.w};
                a0 = fma2(wv[0][2 * i], lo, a0); a0 = fma2(wv[0][2 * i + 1], hi, a0);
                a1 = fma2(wv[1][2 * i], lo, a1); a1 = fma2(wv[1][2 * i + 1], hi, a1);
                a2 = fma2(wv[2][2 * i], lo, a2); a2 = fma2(wv[2][2 * i + 1], hi, a2);
                a3 = fma2(wv[3][2 * i], lo, a3); a3 = fma2(wv[3][2 * i + 1], hi, a3);
            }
            float s0 = red8(a0.x + a0.y);
            float s1 = red8(a1.x + a1.y);
            float s2 = red8(a2.x + a2.y);
            float s3 = red8(a3.x + a3.y);
            if (ko == 0) g4[1][h] = make_float4(s0, s1, s2, s3);
        }
        __syncthreads();

        if (tid < 256) {              // 4 waves: (bl,hh) cell, one h each
            float* h_st = bl ? h_st1 : h_st0;
            float* c_st = bl ? c_st1 : c_st0;
            const int pt = bl ? pt1 : pt0;
            const float4 gg = g4[bl][hh];
            const float gi = gg.x + gxv.x;
            const float gf = gg.y + gxv.y;
            const float gG = gg.z + gxv.z;
            const float go = gg.w + gxv.w;
            const float cc = c_st[pt * Hh + hh];
            const float ch = h_st[pt * Hh + hh];
            const int pv = pt ? (pt - 1) : (S1 - 1);
            const float ph = h_st[pv * Hh + hh];
            const float nc = sigm(gf) * cc + sigm(gi) * tanhx(gG);
            const float nh = sigm(go) * tanhx(nc);
            c_st[(pt + 1) * Hh + hh] = nc;
            h_st[(pt + 1) * Hh + hh] = nh;
            const float opf = (float)opsb[bl][s + 1];
            const float af = fabsf(opf);
            const float ret = (nh * (1.f + opf) + ph * (1.f - opf)) * af + ch * (1.f - af);
            out[((size_t)(t0 + s) * Bb + (b0 + bl)) * Hh + hh] = ret;
            gxv = gxn;
        }
        __syncthreads();
    }

    if (!last) {
        float* hs0 = h_save + (size_t)b0 * (S1 * Hh);
        float* cs0 = c_save + (size_t)b0 * (S1 * Hh);
        float* hs1 = hs0 + (S1 * Hh);
        float* cs1 = cs0 + (S1 * Hh);
        for (int i = tid; i < S1 * Hh; i += 1024) {
            hs0[i] = h_st0[i]; cs0[i] = c_st0[i];
            hs1[i] = h_st1[i]; cs1[i] = c_st1[i];
        }
        if (tid == 0) { pt_save[b0] = pt0; pt_save[b0 + 1] = pt1; }
    }
}

extern "C" void kernel_launch(void* const* d_in, const int* in_sizes, int n_in,
                              void* d_out, int out_size, void* d_ws, size_t ws_size,
                              hipStream_t stream) {
    const float* inputs = (const float*)d_in[0];
    const int*   ops    = (const int*)d_in[1];
    const float* W_ih   = (const float*)d_in[2];
    const float* W_hh   = (const float*)d_in[3];
    const float* b_ih   = (const float*)d_in[4];
    const float* b_hh   = (const float*)d_in[5];
    const float* init_h = (const float*)d_in[6];
    const float* init_c = (const float*)d_in[7];
    float* out = (float*)d_out;

    // Adaptive chunking: if workspace fits the full (511,512,512) gx buffer
    // (~536 MB), do ONE chunk -> no h/c save/restore traffic at all.
    float* ws = (float*)d_ws;
    const size_t gx_full = (size_t)NSTEP * Bb * G4;              // floats
    const size_t save_f  = 2 * (size_t)Bb * S1 * Hh + 512;       // floats
    const size_t ws_f = ws_size / sizeof(float);

    int chcap;
    float *gxbuf, *h_sv, *c_sv;
    int* pt_sv;
    if (ws_f >= gx_full) {
        chcap = NSTEP;
        gxbuf = ws; h_sv = ws; c_sv = ws; pt_sv = (int*)ws;      // save bufs unused
    } else {
        h_sv  = ws;
        c_sv  = h_sv + (size_t)Bb * S1 * Hh;
        pt_sv = (int*)(c_sv + (size_t)Bb * S1 * Hh);
        gxbuf = (float*)(pt_sv + 512);                           // 16B-aligned
        const size_t avail = ws_f > save_f ? ws_f - save_f : 0;
        size_t cc = avail / ((size_t)Bb * G4);
        if (cc < 1) cc = 1;
        chcap = (cc > NSTEP) ? NSTEP : (int)cc;
    }

    int t0 = 0;
    while (t0 < NSTEP) {
        const int steps = (NSTEP - t0 < chcap) ? (NSTEP - t0) : chcap;
        gx_gemm<<<steps * Bb / GROWS, 1024, 0, stream>>>(
            inputs + (size_t)t0 * Bb * Ii, W_ih, b_ih, b_hh, gxbuf, chcap);
        rec_step<<<Bb / 2, 1024, 0, stream>>>(
            gxbuf, ops, W_hh, init_h, init_c, out,
            h_sv, c_sv, pt_sv, t0, steps, chcap,
            (t0 == 0) ? 1 : 0, (t0 + steps >= NSTEP) ? 1 : 0);
        t0 += steps;
    }
}